// Round 1
// baseline (1030.286 us; speedup 1.0000x reference)
//
#include <hip/hip_runtime.h>

typedef unsigned int uint;
typedef unsigned short ushort;
typedef float f32x4 __attribute__((ext_vector_type(4)));
typedef uint u32x4 __attribute__((ext_vector_type(4)));
typedef uint u32x2 __attribute__((ext_vector_type(2)));
typedef __bf16 bf16x8 __attribute__((ext_vector_type(8)));

// Problem constants (fixed by setup_inputs)
constexpr int NR = 150000;   // nodes
constexpr int CD = 256;      // classes == feature dim
constexpr int LR = 50000;    // labeled rows (arange(N) < L)
constexpr int KEX = 56;      // 256 - k(=200): # smallest to exclude per row
constexpr int NUP = 100032;  // padded unlabeled span (1563 * 64)
constexpr int NTP = 150080;  // padded X^T col count (2345 * 64)

__device__ __forceinline__ ushort f2bf(float x) {
  uint u = __builtin_bit_cast(uint, x);
  u += 0x7FFFu + ((u >> 16) & 1u);   // RNE
  return (ushort)(u >> 16);
}
__device__ __forceinline__ uint fkeyu(uint bits) {
  // monotonic float -> uint key (ascending)
  return (bits & 0x80000000u) ? ~bits : (bits | 0x80000000u);
}

// ---------------------------------------------------------------------------
// K1: per-class counts (all rows / labeled rows) + class index per row.
// Thread t owns column t; fully coalesced 1KB row reads.
__global__ __launch_bounds__(256) void k_counts(const float* __restrict__ labels,
                                                int* __restrict__ cls,
                                                float* __restrict__ ca,
                                                float* __restrict__ cl) {
  int t = threadIdx.x;
  int chunk = (NR + 255) / 256;  // 587
  int n0 = blockIdx.x * chunk;
  int n1 = n0 + chunk; if (n1 > NR) n1 = NR;
  float sa = 0.f, sl = 0.f;
  for (int n = n0; n < n1; ++n) {
    float v = labels[n * CD + t];
    if (v > 0.5f) cls[n] = t;
    sa += v;
    if (n < LR) sl += v;
  }
  atomicAdd(&ca[t], sa);
  atomicAdd(&cl[t], sl);
}

// ---------------------------------------------------------------------------
// K2: per-row invnorm + X^T bf16 tiles (transposed through LDS).
__global__ __launch_bounds__(256) void k_prep(const float* __restrict__ X,
                                              ushort* __restrict__ Xt,
                                              float* __restrict__ invn) {
  __shared__ __align__(16) ushort xl[64 * 264];  // [row][f], +8 pad
  __shared__ float red[256];
  int t = threadIdx.x;
  int r = t >> 2, cq = t & 3;
  int g0 = blockIdx.x * 64;
  int g = g0 + r;
  bool valid = g < NR;
  float ss = 0.f;
#pragma unroll
  for (int j = 0; j < 16; ++j) {
    int col = cq * 4 + j * 16;
    f32x4 x = valid ? *reinterpret_cast<const f32x4*>(&X[g * CD + col])
                    : (f32x4){0.f, 0.f, 0.f, 0.f};
    ss += x[0] * x[0] + x[1] * x[1] + x[2] * x[2] + x[3] * x[3];
    uint p0 = (uint)f2bf(x[0]) | ((uint)f2bf(x[1]) << 16);
    uint p1 = (uint)f2bf(x[2]) | ((uint)f2bf(x[3]) << 16);
    *reinterpret_cast<u32x2*>(&xl[r * 264 + col]) = (u32x2){p0, p1};
  }
  red[t] = ss;
  __syncthreads();
  if (t < 64) {
    float s4 = red[t * 4] + red[t * 4 + 1] + red[t * 4 + 2] + red[t * 4 + 3];
    if (g0 + t < NR) invn[g0 + t] = rsqrtf(fmaxf(s4, 1e-12f));
  }
  // phase 2: write X^T[f][g0..g0+63] (raw bf16; zeros for pad rows)
  int f = t;
  uint buf[4];
  for (int n = 0; n < 64; ++n) {
    ushort v16 = xl[n * 264 + f];
    int sl = n & 7;
    if (sl & 1) buf[sl >> 1] |= (uint)v16 << 16; else buf[sl >> 1] = v16;
    if (sl == 7)
      *reinterpret_cast<u32x4*>(&Xt[f * NTP + g0 + n - 7]) =
          (u32x4){buf[0], buf[1], buf[2], buf[3]};
  }
}

// ---------------------------------------------------------------------------
// Split-K GEMM: OUT[c][f] (+)= sum_n A[n][c] * X[n][f], OUT 256x256.
// KIND 0: A = one-hot labels built from cls (rows [0,LR)), KIND 1: A = p^T bf16.
// Each block writes its own 256KB partial slice (no global atomics).
template <int KIND>
__global__ __launch_bounds__(1024) void k_gemmB(const int* __restrict__ cls,
                                                const ushort* __restrict__ Ap,
                                                const ushort* __restrict__ Xt,
                                                float* __restrict__ P,
                                                int nch, int nbase) {
  __shared__ __align__(16) ushort Al[256 * 40];  // [c][n-chunk], +8 pad
  __shared__ __align__(16) ushort Bl[256 * 40];  // [f][n-chunk], +8 pad
  int t = threadIdx.x;
  int lane = t & 63, w = t >> 6;
  int m = lane & 15, qd = lane >> 4;
  f32x4 acc[16];
#pragma unroll
  for (int i = 0; i < 16; ++i) acc[i] = (f32x4){0.f, 0.f, 0.f, 0.f};

  for (int ch = blockIdx.x; ch < nch; ch += gridDim.x) {
    int n0 = ch * 32;
    __syncthreads();
    if (KIND == 0) {
      for (int i = t; i < 5120; i += 1024) reinterpret_cast<uint*>(Al)[i] = 0u;
      __syncthreads();
      if (t < 32) {
        int g = n0 + t;
        if (g < LR) Al[cls[g] * 40 + t] = 0x3F80;  // bf16 1.0
      }
    } else {
      int c = t >> 2, off = (t & 3) * 8;
      *reinterpret_cast<u32x4*>(&Al[c * 40 + off]) =
          *reinterpret_cast<const u32x4*>(&Ap[c * NUP + n0 + off]);
    }
    {
      int fR = t >> 2, off = (t & 3) * 8;
      *reinterpret_cast<u32x4*>(&Bl[fR * 40 + off]) =
          *reinterpret_cast<const u32x4*>(&Xt[fR * NTP + nbase + n0 + off]);
    }
    __syncthreads();
    bf16x8 a = *reinterpret_cast<const bf16x8*>(&Al[(w * 16 + m) * 40 + qd * 8]);
#pragma unroll
    for (int ft = 0; ft < 16; ++ft) {
      bf16x8 b = *reinterpret_cast<const bf16x8*>(&Bl[(ft * 16 + m) * 40 + qd * 8]);
      acc[ft] = __builtin_amdgcn_mfma_f32_16x16x32_bf16(a, b, acc[ft], 0, 0, 0);
    }
  }
  float* Ps = P + (size_t)blockIdx.x * 65536;
#pragma unroll
  for (int ft = 0; ft < 16; ++ft)
#pragma unroll
    for (int r = 0; r < 4; ++r)
      Ps[(w * 16 + qd * 4 + r) * 256 + ft * 16 + m] = acc[ft][r];
}

// ---------------------------------------------------------------------------
// K_protos: reduce partial slices, protos = total/count, normalize -> phat bf16
__global__ __launch_bounds__(256) void k_protos(const float* __restrict__ P, int nsl,
                                                const float* __restrict__ ca,
                                                float* __restrict__ protos,
                                                ushort* __restrict__ phat) {
  __shared__ float red[256];
  int c = blockIdx.x, f = threadIdx.x;
  float s = 0.f;
  for (int i = 0; i < nsl; ++i) s += P[i * 65536 + c * 256 + f];
  float cnt = ca[c];
  float pv = cnt > 0.5f ? s / cnt : 0.f;
  protos[c * 256 + f] = pv;
  red[f] = pv * pv;
  __syncthreads();
  for (int st = 128; st > 0; st >>= 1) {
    if (f < st) red[f] += red[f + st];
    __syncthreads();
  }
  float iv = rsqrtf(fmaxf(red[0], 1e-12f));
  phat[c * 256 + f] = f2bf(pv * iv);
}

// K_update: S reduce + proto update + normalize -> phat2 bf16
__global__ __launch_bounds__(256) void k_update(const float* __restrict__ PS, int nsl,
                                                const float* __restrict__ protos,
                                                const float* __restrict__ q,
                                                const float* __restrict__ clab,
                                                ushort* __restrict__ phat2) {
  __shared__ float red[256];
  int c = blockIdx.x, f = threadIdx.x;
  float s = 0.f;
  for (int i = 0; i < nsl; ++i) s += PS[i * 65536 + c * 256 + f];
  float qc = q[c];
  float den = qc + clab[c];
  float pv = protos[c * 256 + f];
  float np = pv + (s - qc * pv) / den;
  red[f] = np * np;
  __syncthreads();
  for (int st = 128; st > 0; st >>= 1) {
    if (f < st) red[f] += red[f + st];
    __syncthreads();
  }
  float iv = rsqrtf(fmaxf(red[0], 1e-12f));
  phat2[c * 256 + f] = f2bf(np * iv);
}

// ---------------------------------------------------------------------------
// Row GEMM: s[n][c] = l2n(X)[n] . phat[c].  64 rows/block, 4 waves x 16 rows.
// TOPK=1: epilogue does per-row 57th-smallest selection, writes p^T bf16 + q.
// TOPK=0: writes fp32 logits.
template <int TOPK>
__global__ __launch_bounds__(256) void k_passA(const float* __restrict__ X,
                                               const float* __restrict__ invn,
                                               const ushort* __restrict__ Bm,
                                               float* __restrict__ out,
                                               ushort* __restrict__ pt,
                                               float* __restrict__ q,
                                               int gbase) {
  __shared__ __align__(16) ushort Al[64 * 40];
  __shared__ __align__(16) ushort Bl[256 * 40];
  __shared__ __align__(16) ushort s16[TOPK ? 64 * 272 : 64];
  __shared__ uint tkey[TOPK ? 64 : 1];
  int t = threadIdx.x;
  int lane = t & 63, w = t >> 6;
  int m = lane & 15, qd = lane >> 4;
  int g0 = gbase + blockIdx.x * 64;
  int row = t >> 2, off = (t & 3) * 8;
  int g = g0 + row;
  bool valid = g < NR;
  float inv = valid ? invn[g] : 0.f;
  f32x4 acc[16];
#pragma unroll
  for (int i = 0; i < 16; ++i) acc[i] = (f32x4){0.f, 0.f, 0.f, 0.f};

  for (int k0 = 0; k0 < 256; k0 += 32) {
    __syncthreads();
    // stage A: 64 rows x 32 feats, normalized, bf16
    f32x4 x0 = valid ? *reinterpret_cast<const f32x4*>(&X[g * CD + k0 + off])
                     : (f32x4){0.f, 0.f, 0.f, 0.f};
    f32x4 x1 = valid ? *reinterpret_cast<const f32x4*>(&X[g * CD + k0 + off + 4])
                     : (f32x4){0.f, 0.f, 0.f, 0.f};
    x0 *= inv; x1 *= inv;
    uint u0 = (uint)f2bf(x0[0]) | ((uint)f2bf(x0[1]) << 16);
    uint u1 = (uint)f2bf(x0[2]) | ((uint)f2bf(x0[3]) << 16);
    uint u2 = (uint)f2bf(x1[0]) | ((uint)f2bf(x1[1]) << 16);
    uint u3 = (uint)f2bf(x1[2]) | ((uint)f2bf(x1[3]) << 16);
    *reinterpret_cast<u32x4*>(&Al[row * 40 + off]) = (u32x4){u0, u1, u2, u3};
    // stage B: 256 protos x 32 feats bf16
#pragma unroll
    for (int i = 0; i < 4; ++i) {
      int c = (t >> 2) + i * 64;
      *reinterpret_cast<u32x4*>(&Bl[c * 40 + off]) =
          *reinterpret_cast<const u32x4*>(&Bm[c * 256 + k0 + off]);
    }
    __syncthreads();
    bf16x8 a = *reinterpret_cast<const bf16x8*>(&Al[(w * 16 + m) * 40 + qd * 8]);
#pragma unroll
    for (int ft = 0; ft < 16; ++ft) {
      bf16x8 b = *reinterpret_cast<const bf16x8*>(&Bl[(ft * 16 + m) * 40 + qd * 8]);
      acc[ft] = __builtin_amdgcn_mfma_f32_16x16x32_bf16(a, b, acc[ft], 0, 0, 0);
    }
  }

  if (TOPK == 0) {
#pragma unroll
    for (int ft = 0; ft < 16; ++ft)
#pragma unroll
      for (int r = 0; r < 4; ++r) {
        int rr = w * 16 + qd * 4 + r;
        int gg = g0 + rr;
        if (gg < NR) out[gg * 256 + ft * 16 + m] = acc[ft][r];
      }
  } else {
    __syncthreads();  // staging LDS no longer needed; s16 is separate anyway
#pragma unroll
    for (int ft = 0; ft < 16; ++ft)
#pragma unroll
      for (int r = 0; r < 4; ++r)
        s16[(w * 16 + qd * 4 + r) * 272 + ft * 16 + m] = f2bf(acc[ft][r]);
    __syncthreads();
    // phase 2: per row (16 per wave) find 57th-smallest key by bit-bisection
    for (int i = 0; i < 16; ++i) {
      int rw = w * 16 + i;
      u32x2 pk = *reinterpret_cast<const u32x2*>(&s16[rw * 272 + lane * 4]);
      uint kk0 = fkeyu((pk[0] & 0xFFFFu) << 16);
      uint kk1 = fkeyu(pk[0] & 0xFFFF0000u);
      uint kk2 = fkeyu((pk[1] & 0xFFFFu) << 16);
      uint kk3 = fkeyu(pk[1] & 0xFFFF0000u);
      uint mth = 0u;
      for (int b = 31; b >= 0; --b) {
        uint cand = mth | (1u << b);
        int cnt = __builtin_popcountll(__ballot(kk0 < cand)) +
                  __builtin_popcountll(__ballot(kk1 < cand)) +
                  __builtin_popcountll(__ballot(kk2 < cand)) +
                  __builtin_popcountll(__ballot(kk3 < cand));
        if (cnt <= KEX) mth = cand;
      }
      if (lane == 0) tkey[rw] = mth;
    }
    __syncthreads();
    // phase 3: thread t owns class c=t; threshold, q partial, transposed store
    int c = t;
    float qloc = 0.f;
    uint buf[4];
    int n0 = blockIdx.x * 64;
    for (int n = 0; n < 64; ++n) {
      ushort v16 = s16[n * 272 + c];
      uint fb = (uint)v16 << 16;
      bool keep = fkeyu(fb) >= tkey[n];
      ushort pv16 = keep ? v16 : (ushort)0;
      if (keep) qloc += __builtin_bit_cast(float, fb);
      int sl = n & 7;
      if (sl & 1) buf[sl >> 1] |= (uint)pv16 << 16; else buf[sl >> 1] = pv16;
      if (sl == 7)
        *reinterpret_cast<u32x4*>(&pt[c * NUP + n0 + n - 7]) =
            (u32x4){buf[0], buf[1], buf[2], buf[3]};
    }
    atomicAdd(&q[c], qloc);
  }
}

// ---------------------------------------------------------------------------
extern "C" void kernel_launch(void* const* d_in, const int* in_sizes, int n_in,
                              void* d_out, int out_size, void* d_ws, size_t ws_size,
                              hipStream_t stream) {
  const float* inputs = (const float*)d_in[0];
  const float* labels = (const float*)d_in[1];
  float* out = (float*)d_out;

  // d_out doubles as scratch before the final GEMM overwrites it:
  ushort* p_t = (ushort*)d_out;                               // [256][NUP]  51.2 MB
  ushort* Xt  = (ushort*)((char*)d_out + (size_t)256 * NUP * 2);  // [256][NTP] 76.8 MB

  char* ws = (char*)d_ws;
  float* q        = (float*)(ws + 0);        // 1KB
  float* c_all    = (float*)(ws + 1024);     // 1KB
  float* c_lab    = (float*)(ws + 2048);     // 1KB
  float* protos   = (float*)(ws + 4096);     // 256KB
  ushort* phat    = (ushort*)(ws + 4096 + 262144);            // 128KB
  ushort* phat2   = (ushort*)(ws + 4096 + 262144 + 131072);   // 128KB
  float* invn     = (float*)(ws + 528384);   // 600KB
  int*   cls      = (int*)(ws + 1128384);    // 600KB
  size_t base = 1736704;
  int sT = 64, sS = 128;  // partial slices for the two split-K GEMMs
  while (base + (size_t)(sT + sS) * 262144ULL > ws_size && sT > 8) { sT >>= 1; sS >>= 1; }
  float* PT = (float*)(ws + base);
  float* PS = PT + (size_t)sT * 65536;

  hipMemsetAsync(ws, 0, 3072, stream);  // q + counts

  k_counts<<<256, 256, 0, stream>>>(labels, cls, c_all, c_lab);
  k_prep<<<NTP / 64, 256, 0, stream>>>(inputs, Xt, invn);
  k_gemmB<0><<<sT, 1024, 0, stream>>>(cls, nullptr, Xt, PT, 1563, 0);      // total
  k_protos<<<256, 256, 0, stream>>>(PT, sT, c_all, protos, phat);
  k_passA<1><<<NUP / 64, 256, 0, stream>>>(inputs, invn, phat, nullptr, p_t, q, LR);
  k_gemmB<1><<<sS, 1024, 0, stream>>>(nullptr, p_t, Xt, PS, NUP / 32, LR); // S
  k_update<<<256, 256, 0, stream>>>(PS, sS, protos, q, c_lab, phat2);
  k_passA<0><<<(NR + 63) / 64, 256, 0, stream>>>(inputs, invn, phat2, out, nullptr, nullptr, 0);
}

// Round 2
// 793.358 us; speedup vs baseline: 1.2986x; 1.2986x over previous
//
#include <hip/hip_runtime.h>

typedef unsigned int uint;
typedef unsigned short ushort;
typedef float f32x4 __attribute__((ext_vector_type(4)));
typedef uint u32x4 __attribute__((ext_vector_type(4)));
typedef uint u32x2 __attribute__((ext_vector_type(2)));
typedef __bf16 bf16x8 __attribute__((ext_vector_type(8)));

// Problem constants (fixed by setup_inputs)
constexpr int NR = 150000;   // nodes
constexpr int CD = 256;      // classes == feature dim
constexpr int LR = 50000;    // labeled rows (arange(N) < L)
constexpr int KEX = 56;      // 256 - k(=200): # smallest to exclude per row
constexpr int NB1 = 49984;   // 64-aligned base covering unlabeled span
constexpr int NUP = 100032;  // padded span [NB1, NB1+NUP) ⊇ [LR, NR), 1563*64
constexpr int NTP = 150080;  // padded X^T row count (2345 * 64)

__device__ __forceinline__ ushort f2bf(float x) {
  uint u = __builtin_bit_cast(uint, x);
  u += 0x7FFFu + ((u >> 16) & 1u);   // RNE
  return (ushort)(u >> 16);
}
__device__ __forceinline__ uint key16(uint b) {
  // monotonic bf16-bits -> uint16 key (ascending float order)
  return (b & 0x8000u) ? (~b & 0xFFFFu) : (b | 0x8000u);
}

// ---------------------------------------------------------------------------
// K1: wave-per-row one-hot detection + LDS histograms. 1024 blocks.
__global__ __launch_bounds__(256) void k_cls(const float* __restrict__ labels,
                                             int* __restrict__ cls,
                                             float* __restrict__ ca,
                                             float* __restrict__ cl) {
  __shared__ int ha[256], hl[256];
  int t = threadIdx.x;
  ha[t] = 0; hl[t] = 0;
  __syncthreads();
  int lane = t & 63;
  int wid = (blockIdx.x << 2) | (t >> 6);
  int nw = gridDim.x << 2;
  for (int n = wid; n < NR; n += nw) {
    f32x4 v = *reinterpret_cast<const f32x4*>(&labels[n * CD + lane * 4]);
    int j = v[0] > 0.5f ? 0 : v[1] > 0.5f ? 1 : v[2] > 0.5f ? 2 : v[3] > 0.5f ? 3 : -1;
    if (j >= 0) {
      int c = lane * 4 + j;
      cls[n] = c;
      atomicAdd(&ha[c], 1);
      if (n < LR) atomicAdd(&hl[c], 1);
    }
  }
  __syncthreads();
  atomicAdd(&ca[t], (float)ha[t]);
  atomicAdd(&cl[t], (float)hl[t]);
}

// ---------------------------------------------------------------------------
// K2: per-row invnorm + X^T bf16 in block-panel layout [nblk][256f][64n].
__global__ __launch_bounds__(256) void k_prep(const float* __restrict__ X,
                                              ushort* __restrict__ Xt,
                                              float* __restrict__ invn) {
  __shared__ __align__(16) ushort xl[64 * 264];  // [row][f], +8 pad
  __shared__ float red[256];
  int t = threadIdx.x;
  int r = t >> 2, cq = t & 3;
  int g0 = blockIdx.x * 64;
  int g = g0 + r;
  bool valid = g < NR;
  float ss = 0.f;
#pragma unroll
  for (int j = 0; j < 16; ++j) {
    int col = cq * 4 + j * 16;
    f32x4 x = valid ? *reinterpret_cast<const f32x4*>(&X[g * CD + col])
                    : (f32x4){0.f, 0.f, 0.f, 0.f};
    ss += x[0] * x[0] + x[1] * x[1] + x[2] * x[2] + x[3] * x[3];
    uint p0 = (uint)f2bf(x[0]) | ((uint)f2bf(x[1]) << 16);
    uint p1 = (uint)f2bf(x[2]) | ((uint)f2bf(x[3]) << 16);
    *reinterpret_cast<u32x2*>(&xl[r * 264 + col]) = (u32x2){p0, p1};
  }
  red[t] = ss;
  __syncthreads();
  if (t < 64) {
    float s4 = red[t * 4] + red[t * 4 + 1] + red[t * 4 + 2] + red[t * 4 + 3];
    if (g0 + t < NR) invn[g0 + t] = rsqrtf(fmaxf(s4, 1e-12f));
  }
  // phase 2: panel write — block writes contiguous 32KB: Xt[blk][f][n]
  ushort* xp = Xt + (size_t)blockIdx.x * 16384;
  int f = t;
  uint buf[4];
  for (int n = 0; n < 64; ++n) {
    ushort v16 = xl[n * 264 + f];
    int sl = n & 7;
    if (sl & 1) buf[sl >> 1] |= (uint)v16 << 16; else buf[sl >> 1] = v16;
    if (sl == 7)
      *reinterpret_cast<u32x4*>(&xp[f * 64 + n - 7]) =
          (u32x4){buf[0], buf[1], buf[2], buf[3]};
  }
}

// ---------------------------------------------------------------------------
// Split-K GEMM: OUT[c][f] (+)= sum_n A[n][c] * X[n][f], OUT 256x256.
// KIND 0: A = one-hot labels from cls (rows [0,LR)); KIND 1: A = p^T panels.
// Per-block partial slices (no global atomics). Panel layout [blk][256][64].
template <int KIND>
__global__ __launch_bounds__(1024) void k_gemmB(const int* __restrict__ cls,
                                                const ushort* __restrict__ Ap,
                                                const ushort* __restrict__ Xt,
                                                float* __restrict__ P,
                                                int nch, int nbase) {
  __shared__ __align__(16) ushort Al[256 * 40];  // [c][n-chunk], +8 pad
  __shared__ __align__(16) ushort Bl[256 * 40];  // [f][n-chunk], +8 pad
  int t = threadIdx.x;
  int lane = t & 63, w = t >> 6;
  int m = lane & 15, qd = lane >> 4;
  f32x4 acc[16];
#pragma unroll
  for (int i = 0; i < 16; ++i) acc[i] = (f32x4){0.f, 0.f, 0.f, 0.f};

  for (int ch = blockIdx.x; ch < nch; ch += gridDim.x) {
    int n0 = ch * 32;
    __syncthreads();
    if (KIND == 0) {
      for (int i = t; i < 5120; i += 1024) reinterpret_cast<uint*>(Al)[i] = 0u;
      __syncthreads();
      if (t < 32) {
        int g = n0 + t;
        if (g < LR) Al[cls[g] * 40 + t] = 0x3F80;  // bf16 1.0
      }
    } else {
      const ushort* ap = Ap + (size_t)(n0 >> 6) * 16384 + (n0 & 63);
      int c = t >> 2, off = (t & 3) * 8;
      *reinterpret_cast<u32x4*>(&Al[c * 40 + off]) =
          *reinterpret_cast<const u32x4*>(&ap[c * 64 + off]);
    }
    {
      int gr = nbase + n0;
      const ushort* xp = Xt + (size_t)(gr >> 6) * 16384 + (gr & 63);
      int fR = t >> 2, off = (t & 3) * 8;
      *reinterpret_cast<u32x4*>(&Bl[fR * 40 + off]) =
          *reinterpret_cast<const u32x4*>(&xp[fR * 64 + off]);
    }
    __syncthreads();
    bf16x8 a = *reinterpret_cast<const bf16x8*>(&Al[(w * 16 + m) * 40 + qd * 8]);
#pragma unroll
    for (int ft = 0; ft < 16; ++ft) {
      bf16x8 b = *reinterpret_cast<const bf16x8*>(&Bl[(ft * 16 + m) * 40 + qd * 8]);
      acc[ft] = __builtin_amdgcn_mfma_f32_16x16x32_bf16(a, b, acc[ft], 0, 0, 0);
    }
  }
  float* Ps = P + (size_t)blockIdx.x * 65536;
#pragma unroll
  for (int ft = 0; ft < 16; ++ft)
#pragma unroll
    for (int r = 0; r < 4; ++r)
      Ps[(w * 16 + qd * 4 + r) * 256 + ft * 16 + m] = acc[ft][r];
}

// ---------------------------------------------------------------------------
// K_protos: reduce partial slices, protos = total/count, normalize -> phat bf16
__global__ __launch_bounds__(256) void k_protos(const float* __restrict__ P, int nsl,
                                                const float* __restrict__ ca,
                                                float* __restrict__ protos,
                                                ushort* __restrict__ phat) {
  __shared__ float red[256];
  int c = blockIdx.x, f = threadIdx.x;
  float s = 0.f;
  for (int i = 0; i < nsl; ++i) s += P[i * 65536 + c * 256 + f];
  float cnt = ca[c];
  float pv = cnt > 0.5f ? s / cnt : 0.f;
  protos[c * 256 + f] = pv;
  red[f] = pv * pv;
  __syncthreads();
  for (int st = 128; st > 0; st >>= 1) {
    if (f < st) red[f] += red[f + st];
    __syncthreads();
  }
  float iv = rsqrtf(fmaxf(red[0], 1e-12f));
  phat[c * 256 + f] = f2bf(pv * iv);
}

// K_update: S reduce + proto update + normalize -> phat2 bf16
__global__ __launch_bounds__(256) void k_update(const float* __restrict__ PS, int nsl,
                                                const float* __restrict__ protos,
                                                const float* __restrict__ q,
                                                const float* __restrict__ clab,
                                                ushort* __restrict__ phat2) {
  __shared__ float red[256];
  int c = blockIdx.x, f = threadIdx.x;
  float s = 0.f;
  for (int i = 0; i < nsl; ++i) s += PS[i * 65536 + c * 256 + f];
  float qc = q[c];
  float den = qc + clab[c];
  float pv = protos[c * 256 + f];
  float np = pv + (s - qc * pv) / den;
  red[f] = np * np;
  __syncthreads();
  for (int st = 128; st > 0; st >>= 1) {
    if (f < st) red[f] += red[f + st];
    __syncthreads();
  }
  float iv = rsqrtf(fmaxf(red[0], 1e-12f));
  phat2[c * 256 + f] = f2bf(np * iv);
}

// ---------------------------------------------------------------------------
// Row GEMM: s[n][c] = l2n(X)[n] . phat[c].  64 rows/block, 4 waves x 16 rows.
// TOPK=1: per-row 57th-smallest selection (16-bit bisection), p^T panels + q.
// TOPK=0: fp32 logits to out.
template <int TOPK>
__global__ __launch_bounds__(256) void k_passA(const float* __restrict__ X,
                                               const float* __restrict__ invn,
                                               const ushort* __restrict__ Bm,
                                               float* __restrict__ out,
                                               ushort* __restrict__ pt,
                                               float* __restrict__ q,
                                               int gbase) {
  __shared__ __align__(16) ushort Al[64 * 40];
  __shared__ __align__(16) ushort Bl[256 * 40];
  __shared__ __align__(16) ushort s16[TOPK ? 64 * 272 : 64];
  __shared__ uint tkey[TOPK ? 64 : 1];
  int t = threadIdx.x;
  int lane = t & 63, w = t >> 6;
  int m = lane & 15, qd = lane >> 4;
  int g0 = gbase + blockIdx.x * 64;
  int row = t >> 2, off = (t & 3) * 8;
  int g = g0 + row;
  bool valid = g < NR;
  float inv = valid ? invn[g] : 0.f;
  f32x4 acc[16];
#pragma unroll
  for (int i = 0; i < 16; ++i) acc[i] = (f32x4){0.f, 0.f, 0.f, 0.f};

  for (int k0 = 0; k0 < 256; k0 += 32) {
    __syncthreads();
    f32x4 x0 = valid ? *reinterpret_cast<const f32x4*>(&X[g * CD + k0 + off])
                     : (f32x4){0.f, 0.f, 0.f, 0.f};
    f32x4 x1 = valid ? *reinterpret_cast<const f32x4*>(&X[g * CD + k0 + off + 4])
                     : (f32x4){0.f, 0.f, 0.f, 0.f};
    x0 *= inv; x1 *= inv;
    uint u0 = (uint)f2bf(x0[0]) | ((uint)f2bf(x0[1]) << 16);
    uint u1 = (uint)f2bf(x0[2]) | ((uint)f2bf(x0[3]) << 16);
    uint u2 = (uint)f2bf(x1[0]) | ((uint)f2bf(x1[1]) << 16);
    uint u3 = (uint)f2bf(x1[2]) | ((uint)f2bf(x1[3]) << 16);
    *reinterpret_cast<u32x4*>(&Al[row * 40 + off]) = (u32x4){u0, u1, u2, u3};
#pragma unroll
    for (int i = 0; i < 4; ++i) {
      int c = (t >> 2) + i * 64;
      *reinterpret_cast<u32x4*>(&Bl[c * 40 + off]) =
          *reinterpret_cast<const u32x4*>(&Bm[c * 256 + k0 + off]);
    }
    __syncthreads();
    bf16x8 a = *reinterpret_cast<const bf16x8*>(&Al[(w * 16 + m) * 40 + qd * 8]);
#pragma unroll
    for (int ft = 0; ft < 16; ++ft) {
      bf16x8 b = *reinterpret_cast<const bf16x8*>(&Bl[(ft * 16 + m) * 40 + qd * 8]);
      acc[ft] = __builtin_amdgcn_mfma_f32_16x16x32_bf16(a, b, acc[ft], 0, 0, 0);
    }
  }

  if (TOPK == 0) {
#pragma unroll
    for (int ft = 0; ft < 16; ++ft)
#pragma unroll
      for (int r = 0; r < 4; ++r) {
        int rr = w * 16 + qd * 4 + r;
        int gg = g0 + rr;
        if (gg < NR) out[gg * 256 + ft * 16 + m] = acc[ft][r];
      }
  } else {
    __syncthreads();
#pragma unroll
    for (int ft = 0; ft < 16; ++ft)
#pragma unroll
      for (int r = 0; r < 4; ++r)
        s16[(w * 16 + qd * 4 + r) * 272 + ft * 16 + m] = f2bf(acc[ft][r]);
    __syncthreads();
    // phase 2: per row, 57th-smallest via 16-step bit-bisection on bf16 keys
    for (int i = 0; i < 16; ++i) {
      int rw = w * 16 + i;
      u32x2 pk = *reinterpret_cast<const u32x2*>(&s16[rw * 272 + lane * 4]);
      uint k0 = key16(pk[0] & 0xFFFFu);
      uint k1 = key16(pk[0] >> 16);
      uint k2 = key16(pk[1] & 0xFFFFu);
      uint k3 = key16(pk[1] >> 16);
      uint mth = 0u;
      for (int b = 15; b >= 0; --b) {
        uint cand = mth | (1u << b);
        int cnt = __builtin_popcountll(__ballot(k0 < cand)) +
                  __builtin_popcountll(__ballot(k1 < cand)) +
                  __builtin_popcountll(__ballot(k2 < cand)) +
                  __builtin_popcountll(__ballot(k3 < cand));
        if (cnt <= KEX) mth = cand;
      }
      if (lane == 0) tkey[rw] = mth;
    }
    __syncthreads();
    // phase 3: thread t owns class c=t; threshold + um mask, q partial,
    // p^T panel write (contiguous 32KB per block)
    int c = t;
    float qloc = 0.f;
    uint buf[4];
    ushort* pp = pt + (size_t)blockIdx.x * 16384;
    for (int n = 0; n < 64; ++n) {
      int grow = g0 + n;
      ushort v16 = s16[n * 272 + c];
      bool keep = (key16(v16) >= tkey[n]) && (grow >= LR) && (grow < NR);
      ushort pv16 = keep ? v16 : (ushort)0;
      if (keep) qloc += __builtin_bit_cast(float, (uint)v16 << 16);
      int sl = n & 7;
      if (sl & 1) buf[sl >> 1] |= (uint)pv16 << 16; else buf[sl >> 1] = pv16;
      if (sl == 7)
        *reinterpret_cast<u32x4*>(&pp[c * 64 + n - 7]) =
            (u32x4){buf[0], buf[1], buf[2], buf[3]};
    }
    atomicAdd(&q[c], qloc);
  }
}

// ---------------------------------------------------------------------------
extern "C" void kernel_launch(void* const* d_in, const int* in_sizes, int n_in,
                              void* d_out, int out_size, void* d_ws, size_t ws_size,
                              hipStream_t stream) {
  const float* inputs = (const float*)d_in[0];
  const float* labels = (const float*)d_in[1];
  float* out = (float*)d_out;

  // d_out doubles as scratch before the final GEMM overwrites it:
  ushort* p_t = (ushort*)d_out;                                  // panels, 51.2 MB
  ushort* Xt  = (ushort*)((char*)d_out + (size_t)256 * NUP * 2); // panels, 76.8 MB

  char* ws = (char*)d_ws;
  float* q      = (float*)(ws + 0);
  float* c_all  = (float*)(ws + 1024);
  float* c_lab  = (float*)(ws + 2048);
  float* protos = (float*)(ws + 4096);
  ushort* phat  = (ushort*)(ws + 4096 + 262144);
  ushort* phat2 = (ushort*)(ws + 4096 + 262144 + 131072);
  float* invn   = (float*)(ws + 528384);
  int*   cls    = (int*)(ws + 1128384);
  size_t base = 1736704;
  int sT = 128, sS = 256;  // partial-slice counts for the two split-K GEMMs
  while (base + (size_t)(sT + sS) * 262144ULL > ws_size) {
    if (sS > sT) sS >>= 1; else if (sT > 8) sT >>= 1; else break;
  }
  float* PT = (float*)(ws + base);
  float* PS = PT + (size_t)sT * 65536;

  hipMemsetAsync(ws, 0, 3072, stream);  // q + counts

  k_cls<<<1024, 256, 0, stream>>>(labels, cls, c_all, c_lab);
  k_prep<<<NTP / 64, 256, 0, stream>>>(inputs, Xt, invn);
  k_gemmB<0><<<sT, 1024, 0, stream>>>(cls, nullptr, Xt, PT, 1563, 0);        // total
  k_protos<<<256, 256, 0, stream>>>(PT, sT, c_all, protos, phat);
  k_passA<1><<<NUP / 64, 256, 0, stream>>>(inputs, invn, phat, nullptr, p_t, q, NB1);
  k_gemmB<1><<<sS, 1024, 0, stream>>>(nullptr, p_t, Xt, PS, NUP / 32, NB1);  // S
  k_update<<<256, 256, 0, stream>>>(PS, sS, protos, q, c_lab, phat2);
  k_passA<0><<<(NR + 63) / 64, 256, 0, stream>>>(inputs, invn, phat2, out, nullptr, nullptr, 0);
}